// Round 1
// baseline (51238.708 us; speedup 1.0000x reference)
//
#include <hip/hip_runtime.h>
#include <math.h>

// Problem constants
#define BB 8
#define HH 64
#define WW 64
#define CC 64
#define CI 32
#define NP 256   // hs*ws = 16*16
// Workspace layout (floats)
#define THETA_OFF 0u
#define G_OFF     1048576u     // 8*4096*32
#define PHI_OFF   3145728u     // + 8*4096*64
#define PHIN_OFF  3211264u     // + 8*256*32
#define ATTN_OFF  3801088u     // + 8*288*256
// total 12,189,696 floats = 48.8 MB of d_ws

// ---------------- K1: theta & g conv1x1 + prelu ----------------
__global__ void k_theta_g(const float* __restrict__ x,
                          const float* __restrict__ theta_w, const float* __restrict__ theta_b,
                          const float* __restrict__ theta_alpha,
                          const float* __restrict__ g_w, const float* __restrict__ g_b,
                          const float* __restrict__ g_alpha,
                          float* __restrict__ theta, float* __restrict__ g) {
  int pix = blockIdx.x;            // b*4096 + h*64 + w
  int tid = threadIdx.x;           // 0..63
  __shared__ float xs[64];
  xs[tid] = x[(size_t)pix * 64 + tid];
  __syncthreads();
  float gacc = g_b[tid];
  #pragma unroll
  for (int k = 0; k < 64; ++k) gacc += xs[k] * g_w[k * 64 + tid];
  float ga = g_alpha[tid];
  g[(size_t)pix * 64 + tid] = gacc >= 0.f ? gacc : ga * gacc;
  if (tid < 32) {
    float tacc = theta_b[tid];
    #pragma unroll
    for (int k = 0; k < 64; ++k) tacc += xs[k] * theta_w[k * 32 + tid];
    float ta = theta_alpha[tid];
    theta[(size_t)pix * 32 + tid] = tacc >= 0.f ? tacc : ta * tacc;
  }
}

// ---------------- K2a: bilinear 64->16 (exact 2x2 avg) + phi conv ----------------
__global__ void k_phi(const float* __restrict__ x,
                      const float* __restrict__ phi_w, const float* __restrict__ phi_b,
                      const float* __restrict__ phi_alpha,
                      float* __restrict__ phi) {
  int bid = blockIdx.x;            // b*256 + i*16 + j
  int b = bid >> 8; int ij = bid & 255; int i = ij >> 4; int j = ij & 15;
  int tid = threadIdx.x;           // 0..63
  __shared__ float ps[64];
  const float* xb = x + (size_t)b * HH * WW * CC;
  int r0 = 4 * i + 1, c0 = 4 * j + 1;
  float v = 0.25f * ( xb[((size_t)r0 * 64 + c0) * 64 + tid]
                    + xb[((size_t)r0 * 64 + c0 + 1) * 64 + tid]
                    + xb[((size_t)(r0 + 1) * 64 + c0) * 64 + tid]
                    + xb[((size_t)(r0 + 1) * 64 + c0 + 1) * 64 + tid]);
  ps[tid] = v;
  __syncthreads();
  if (tid < 32) {
    float acc = phi_b[tid];
    #pragma unroll
    for (int k = 0; k < 64; ++k) acc += ps[k] * phi_w[k * 32 + tid];
    float a = phi_alpha[tid];
    phi[(size_t)bid * 32 + tid] = acc >= 0.f ? acc : a * acc;
  }
}

// ---------------- K2b: phi patches, L2-normalize, store transposed [b][k=288][n=256] ----------------
__global__ void k_phin(const float* __restrict__ phi, float* __restrict__ phi_nT) {
  int bid = blockIdx.x;            // b*256 + n
  int b = bid >> 8; int n = bid & 255; int i = n >> 4; int j = n & 15;
  int t = threadIdx.x;             // 0..319 (288 active)
  float val = 0.f;
  if (t < 288) {
    int di = t / 96; int rem = t % 96; int dj = rem >> 5; int ci = rem & 31;
    int pi = i + di - 1, pj = j + dj - 1;
    if (pi >= 0 && pi < 16 && pj >= 0 && pj < 16)
      val = phi[(((size_t)b * 16 + pi) * 16 + pj) * 32 + ci];
  }
  float ss = val * val;
  for (int off = 32; off > 0; off >>= 1) ss += __shfl_down(ss, off);
  __shared__ float red[5];
  int wid = t >> 6, lane = t & 63;
  if (lane == 0) red[wid] = ss;
  __syncthreads();
  float tot = red[0] + red[1] + red[2] + red[3] + red[4];
  float scale = 1.f / fmaxf(sqrtf(tot), 1e-6f);
  if (t < 288) phi_nT[((size_t)b * 288 + t) * 256 + n] = val * scale;
}

// ---------------- K3: scores (theta_patch . phi_n) + softmax -> attn ----------------
__global__ __launch_bounds__(256) void k_attn(const float* __restrict__ theta,
                                              const float* __restrict__ phi_nT,
                                              float* __restrict__ attn) {
  int bid = blockIdx.x;            // b*1024 + h*16 + wg
  int b = bid >> 10; int rem = bid & 1023; int h = rem >> 4; int w0 = (rem & 15) * 4;
  int n = threadIdx.x;             // 0..255 (= patch index)
  __shared__ float tv[4 * 288];
  __shared__ float ph[32 * 256];
  __shared__ float wred[4][4];
  // theta patches for 4 consecutive-w pixels
  for (int idx = n; idx < 4 * 288; idx += 256) {
    int pix = idx / 288; int k = idx % 288;
    int di = k / 96; int r2 = k % 96; int dj = r2 >> 5; int ci = r2 & 31;
    int hh = h + di - 1; int ww = w0 + pix + dj - 1;
    float v = 0.f;
    if (hh >= 0 && hh < 64 && ww >= 0 && ww < 64)
      v = theta[(((size_t)b * 64 + hh) * 64 + ww) * 32 + ci];
    tv[idx] = v;
  }
  float acc0 = 0.f, acc1 = 0.f, acc2 = 0.f, acc3 = 0.f;
  const float* pbase = phi_nT + (size_t)b * 288 * 256;
  for (int kc = 0; kc < 9; ++kc) {
    __syncthreads();
    #pragma unroll
    for (int rr = 0; rr < 32; ++rr)
      ph[rr * 256 + n] = pbase[(size_t)(kc * 32 + rr) * 256 + n];
    __syncthreads();
    #pragma unroll
    for (int rr = 0; rr < 32; ++rr) {
      float pv = ph[rr * 256 + n];
      int k = kc * 32 + rr;
      acc0 += tv[0 * 288 + k] * pv;
      acc1 += tv[1 * 288 + k] * pv;
      acc2 += tv[2 * 288 + k] * pv;
      acc3 += tv[3 * 288 + k] * pv;
    }
  }
  float sc[4] = {acc0 * 10.f, acc1 * 10.f, acc2 * 10.f, acc3 * 10.f};
  int wid = n >> 6;
  // block max per pixel
  #pragma unroll
  for (int p = 0; p < 4; ++p) {
    float m = sc[p];
    for (int off = 32; off > 0; off >>= 1) m = fmaxf(m, __shfl_down(m, off));
    if ((n & 63) == 0) wred[p][wid] = m;
  }
  __syncthreads();
  float e[4];
  #pragma unroll
  for (int p = 0; p < 4; ++p) {
    float mx = fmaxf(fmaxf(wred[p][0], wred[p][1]), fmaxf(wred[p][2], wred[p][3]));
    e[p] = expf(sc[p] - mx);
  }
  __syncthreads();
  #pragma unroll
  for (int p = 0; p < 4; ++p) {
    float s2 = e[p];
    for (int off = 32; off > 0; off >>= 1) s2 += __shfl_down(s2, off);
    if ((n & 63) == 0) wred[p][wid] = s2;
  }
  __syncthreads();
  #pragma unroll
  for (int p = 0; p < 4; ++p) {
    float tot = wred[p][0] + wred[p][1] + wred[p][2] + wred[p][3];
    attn[(((size_t)b * 64 + h) * 64 + (w0 + p)) * 256 + n] = e[p] / tot;
  }
}

// ---------------- K4: transposed-conv combine ----------------
// out[b, 4*qy+ry, 4*qx+rx, c] = (1/6) * sum_{dy,dx in [0,3)} sum_{n=(i,j)}
//   attn[b, qy+1-dy, qx+1-dx, n] * g[b, 4i + (ry+4dy) - 4, 4j + (rx+4dx) - 4, c]
__global__ __launch_bounds__(256) void k_deconv(const float* __restrict__ attn,
                                                const float* __restrict__ g,
                                                float* __restrict__ out) {
  int bid = blockIdx.x;            // ((b*16 + r)*16 + qt)
  int qt = bid & 15; int r = (bid >> 4) & 15; int b = bid >> 8;
  int r_y = r >> 2, r_x = r & 3;
  int tid = threadIdx.x;
  int q_y = qt * 4 + (tid >> 6);
  int q_x = tid & 63;
  __shared__ float Bs[64][68];     // [k_local][c], stride 68 to break write conflicts
  float acc[64];
  #pragma unroll
  for (int c = 0; c < 64; ++c) acc[c] = 0.f;
  const float* gb = g + (size_t)b * 64 * 64 * 64;
  const float* ab = attn + (size_t)b * 64 * 64 * 256;

  for (int dy = 0; dy < 3; ++dy) {
    int h = q_y + 1 - dy;
    int u = r_y + 4 * dy;
    for (int dx = 0; dx < 3; ++dx) {
      int w = q_x + 1 - dx;
      int v = r_x + 4 * dx;
      bool valid = (h >= 0) && (h < 64) && (w >= 0) && (w < 64);
      int hc = valid ? h : 0;
      int wc = valid ? w : 0;
      const float4* arow = (const float4*)(ab + (((size_t)hc * 64 + wc) << 8));
      for (int kc = 0; kc < 4; ++kc) {
        __syncthreads();
        {
          int kl = tid >> 2;
          int c0 = (tid & 3) * 16;
          int nn = kc * 64 + kl;
          int gi = nn >> 4, gj = nn & 15;
          int grow = 4 * gi + u - 4;
          int gcol = 4 * gj + v - 4;
          float4* dst = (float4*)(&Bs[kl][c0]);
          if (grow >= 0 && grow < 64 && gcol >= 0 && gcol < 64) {
            const float4* src = (const float4*)(gb + (((size_t)grow * 64 + gcol) << 6) + c0);
            #pragma unroll
            for (int q = 0; q < 4; ++q) dst[q] = src[q];
          } else {
            float4 z = make_float4(0.f, 0.f, 0.f, 0.f);
            #pragma unroll
            for (int q = 0; q < 4; ++q) dst[q] = z;
          }
        }
        __syncthreads();
        #pragma unroll 4
        for (int k4 = 0; k4 < 16; ++k4) {
          float4 a4 = valid ? arow[kc * 16 + k4] : make_float4(0.f, 0.f, 0.f, 0.f);
          #pragma unroll
          for (int kk = 0; kk < 4; ++kk) {
            float a = (&a4.x)[kk];
            const float4* brow = (const float4*)(&Bs[k4 * 4 + kk][0]);
            #pragma unroll
            for (int c4 = 0; c4 < 16; ++c4) {
              float4 bv = brow[c4];
              acc[c4 * 4 + 0] += a * bv.x;
              acc[c4 * 4 + 1] += a * bv.y;
              acc[c4 * 4 + 2] += a * bv.z;
              acc[c4 * 4 + 3] += a * bv.w;
            }
          }
        }
      }
    }
  }
  int oy = 4 * q_y + r_y, ox = 4 * q_x + r_x;
  float4* op = (float4*)(out + (((size_t)b * 256 + oy) * 256 + ox) * 64);
  const float inv6 = 1.f / 6.f;
  #pragma unroll
  for (int c4 = 0; c4 < 16; ++c4) {
    float4 v4;
    v4.x = acc[c4 * 4 + 0] * inv6;
    v4.y = acc[c4 * 4 + 1] * inv6;
    v4.z = acc[c4 * 4 + 2] * inv6;
    v4.w = acc[c4 * 4 + 3] * inv6;
    op[c4] = v4;
  }
}

extern "C" void kernel_launch(void* const* d_in, const int* in_sizes, int n_in,
                              void* d_out, int out_size, void* d_ws, size_t ws_size,
                              hipStream_t stream) {
  const float* x           = (const float*)d_in[0];
  const float* theta_w     = (const float*)d_in[1];
  const float* theta_b     = (const float*)d_in[2];
  const float* theta_alpha = (const float*)d_in[3];
  const float* phi_w       = (const float*)d_in[4];
  const float* phi_b       = (const float*)d_in[5];
  const float* phi_alpha   = (const float*)d_in[6];
  const float* g_w         = (const float*)d_in[7];
  const float* g_b         = (const float*)d_in[8];
  const float* g_alpha     = (const float*)d_in[9];
  float* out = (float*)d_out;
  float* ws  = (float*)d_ws;

  float* theta  = ws + THETA_OFF;
  float* g      = ws + G_OFF;
  float* phi    = ws + PHI_OFF;
  float* phi_nT = ws + PHIN_OFF;
  float* attn   = ws + ATTN_OFF;

  hipLaunchKernelGGL(k_theta_g, dim3(BB * HH * WW), dim3(64), 0, stream,
                     x, theta_w, theta_b, theta_alpha, g_w, g_b, g_alpha, theta, g);
  hipLaunchKernelGGL(k_phi, dim3(BB * 256), dim3(64), 0, stream,
                     x, phi_w, phi_b, phi_alpha, phi);
  hipLaunchKernelGGL(k_phin, dim3(BB * 256), dim3(320), 0, stream, phi, phi_nT);
  hipLaunchKernelGGL(k_attn, dim3(BB * 64 * 16), dim3(256), 0, stream,
                     theta, phi_nT, attn);
  hipLaunchKernelGGL(k_deconv, dim3(BB * 16 * 16), dim3(256), 0, stream,
                     attn, g, out);
}

// Round 2
// 858.955 us; speedup vs baseline: 59.6524x; 59.6524x over previous
//
#include <hip/hip_runtime.h>
#include <math.h>

// Problem constants: B=8, H=W=64, C=64, CI=32, SCALE=4, PATCH=3, N=256, K=9*256=2304
#define BB 8

typedef __attribute__((ext_vector_type(8))) short short8;   // 8 x bf16 bits
typedef __attribute__((ext_vector_type(4))) float f32x4;

__device__ inline short f2bf(float x) {          // fp32 -> bf16 (RNE)
  unsigned u = __builtin_bit_cast(unsigned, x);
  u += 0x7fffu + ((u >> 16) & 1u);
  return (short)(u >> 16);
}

__device__ inline void gload_lds16(const void* g, void* l) {
  __builtin_amdgcn_global_load_lds(
      (const __attribute__((address_space(1))) void*)g,
      (__attribute__((address_space(3))) void*)l, 16, 0, 0);
}

// ---------------- K1: theta & g conv1x1 + prelu ----------------
__global__ void k_theta_g(const float* __restrict__ x,
                          const float* __restrict__ theta_w, const float* __restrict__ theta_b,
                          const float* __restrict__ theta_alpha,
                          const float* __restrict__ g_w, const float* __restrict__ g_b,
                          const float* __restrict__ g_alpha,
                          float* __restrict__ theta, float* __restrict__ g) {
  int pix = blockIdx.x;            // b*4096 + h*64 + w
  int tid = threadIdx.x;           // 0..63
  __shared__ float xs[64];
  xs[tid] = x[(size_t)pix * 64 + tid];
  __syncthreads();
  float gacc = g_b[tid];
  #pragma unroll
  for (int k = 0; k < 64; ++k) gacc += xs[k] * g_w[k * 64 + tid];
  float ga = g_alpha[tid];
  g[(size_t)pix * 64 + tid] = gacc >= 0.f ? gacc : ga * gacc;
  if (tid < 32) {
    float tacc = theta_b[tid];
    #pragma unroll
    for (int k = 0; k < 64; ++k) tacc += xs[k] * theta_w[k * 32 + tid];
    float ta = theta_alpha[tid];
    theta[(size_t)pix * 32 + tid] = tacc >= 0.f ? tacc : ta * tacc;
  }
}

// ---------------- K2a: bilinear 64->16 (exact 2x2 avg) + phi conv ----------------
__global__ void k_phi(const float* __restrict__ x,
                      const float* __restrict__ phi_w, const float* __restrict__ phi_b,
                      const float* __restrict__ phi_alpha,
                      float* __restrict__ phi) {
  int bid = blockIdx.x;            // b*256 + i*16 + j
  int b = bid >> 8; int ij = bid & 255; int i = ij >> 4; int j = ij & 15;
  int tid = threadIdx.x;           // 0..63
  __shared__ float ps[64];
  const float* xb = x + (size_t)b * 64 * 64 * 64;
  int r0 = 4 * i + 1, c0 = 4 * j + 1;
  float v = 0.25f * ( xb[((size_t)r0 * 64 + c0) * 64 + tid]
                    + xb[((size_t)r0 * 64 + c0 + 1) * 64 + tid]
                    + xb[((size_t)(r0 + 1) * 64 + c0) * 64 + tid]
                    + xb[((size_t)(r0 + 1) * 64 + c0 + 1) * 64 + tid]);
  ps[tid] = v;
  __syncthreads();
  if (tid < 32) {
    float acc = phi_b[tid];
    #pragma unroll
    for (int k = 0; k < 64; ++k) acc += ps[k] * phi_w[k * 32 + tid];
    float a = phi_alpha[tid];
    phi[(size_t)bid * 32 + tid] = acc >= 0.f ? acc : a * acc;
  }
}

// ---------------- K2b: phi patches, L2-normalize, store transposed [b][k=288][n=256] ----------------
__global__ void k_phin(const float* __restrict__ phi, float* __restrict__ phi_nT) {
  int bid = blockIdx.x;            // b*256 + n
  int b = bid >> 8; int n = bid & 255; int i = n >> 4; int j = n & 15;
  int t = threadIdx.x;             // 0..319 (288 active)
  float val = 0.f;
  if (t < 288) {
    int di = t / 96; int rem = t % 96; int dj = rem >> 5; int ci = rem & 31;
    int pi = i + di - 1, pj = j + dj - 1;
    if (pi >= 0 && pi < 16 && pj >= 0 && pj < 16)
      val = phi[(((size_t)b * 16 + pi) * 16 + pj) * 32 + ci];
  }
  float ss = val * val;
  for (int off = 32; off > 0; off >>= 1) ss += __shfl_down(ss, off);
  __shared__ float red[5];
  int wid = t >> 6, lane = t & 63;
  if (lane == 0) red[wid] = ss;
  __syncthreads();
  float tot = red[0] + red[1] + red[2] + red[3] + red[4];
  float scale = 1.f / fmaxf(sqrtf(tot), 1e-6f);
  if (t < 288) phi_nT[((size_t)b * 288 + t) * 256 + n] = val * scale;
}

// ---------------- K3: scores + softmax -> attnp (bf16, zero-padded [b][66][66][256]) ----------------
__global__ __launch_bounds__(256) void k_attn(const float* __restrict__ theta,
                                              const float* __restrict__ phi_nT,
                                              short* __restrict__ attnp) {
  int bid = blockIdx.x;            // b*1024 + h*16 + wg
  int b = bid >> 10; int rem = bid & 1023; int h = rem >> 4; int w0 = (rem & 15) * 4;
  int n = threadIdx.x;             // 0..255 (= patch index)
  __shared__ float tv[4 * 288];
  __shared__ float ph[32 * 256];
  __shared__ float wred[4][4];
  for (int idx = n; idx < 4 * 288; idx += 256) {
    int pix = idx / 288; int k = idx % 288;
    int di = k / 96; int r2 = k % 96; int dj = r2 >> 5; int ci = r2 & 31;
    int hh = h + di - 1; int ww = w0 + pix + dj - 1;
    float v = 0.f;
    if (hh >= 0 && hh < 64 && ww >= 0 && ww < 64)
      v = theta[(((size_t)b * 64 + hh) * 64 + ww) * 32 + ci];
    tv[idx] = v;
  }
  float acc0 = 0.f, acc1 = 0.f, acc2 = 0.f, acc3 = 0.f;
  const float* pbase = phi_nT + (size_t)b * 288 * 256;
  for (int kc = 0; kc < 9; ++kc) {
    __syncthreads();
    #pragma unroll
    for (int rr = 0; rr < 32; ++rr)
      ph[rr * 256 + n] = pbase[(size_t)(kc * 32 + rr) * 256 + n];
    __syncthreads();
    #pragma unroll
    for (int rr = 0; rr < 32; ++rr) {
      float pv = ph[rr * 256 + n];
      int k = kc * 32 + rr;
      acc0 += tv[0 * 288 + k] * pv;
      acc1 += tv[1 * 288 + k] * pv;
      acc2 += tv[2 * 288 + k] * pv;
      acc3 += tv[3 * 288 + k] * pv;
    }
  }
  float sc[4] = {acc0 * 10.f, acc1 * 10.f, acc2 * 10.f, acc3 * 10.f};
  int wid = n >> 6;
  #pragma unroll
  for (int p = 0; p < 4; ++p) {
    float m = sc[p];
    for (int off = 32; off > 0; off >>= 1) m = fmaxf(m, __shfl_down(m, off));
    if ((n & 63) == 0) wred[p][wid] = m;
  }
  __syncthreads();
  float e[4];
  #pragma unroll
  for (int p = 0; p < 4; ++p) {
    float mx = fmaxf(fmaxf(wred[p][0], wred[p][1]), fmaxf(wred[p][2], wred[p][3]));
    e[p] = expf(sc[p] - mx);
  }
  __syncthreads();
  #pragma unroll
  for (int p = 0; p < 4; ++p) {
    float s2 = e[p];
    for (int off = 32; off > 0; off >>= 1) s2 += __shfl_down(s2, off);
    if ((n & 63) == 0) wred[p][wid] = s2;
  }
  __syncthreads();
  #pragma unroll
  for (int p = 0; p < 4; ++p) {
    float tot = wred[p][0] + wred[p][1] + wred[p][2] + wred[p][3];
    attnp[(((size_t)b * 66 + (h + 1)) * 66 + (w0 + p + 1)) * 256 + n] = f2bf(e[p] / tot);
  }
}

// ---------------- K4a: gather g -> Bbf[b][n=(ry,rx,c)=1024][k=(dy,dx,i,j)=2304] bf16 ----------------
__global__ __launch_bounds__(256) void k_bgather(const float* __restrict__ g,  // base at batch b0
                                                 short* __restrict__ Bbf) {
  int bid = blockIdx.x;            // bl*1024 + n
  int bl = bid >> 10; int n = bid & 1023;
  int r = n >> 6; int ry = r >> 2; int rx = r & 3; int c = n & 63;
  int tid = threadIdx.x;           // = i*16 + j
  int i = tid >> 4; int j = tid & 15;
  const float* gb = g + (size_t)bl * 64 * 64 * 64;
  short* dst = Bbf + ((size_t)bl * 1024 + n) * 2304;
  #pragma unroll
  for (int s = 0; s < 9; ++s) {
    int dy = s / 3, dx = s % 3;
    int row = 4 * i + ry + 4 * dy - 4;
    int col = 4 * j + rx + 4 * dx - 4;
    float v = 0.f;
    if (row >= 0 && row < 64 && col >= 0 && col < 64)
      v = gb[(((size_t)row << 6) + col) * 64 + c];
    dst[s * 256 + tid] = f2bf(v);
  }
}

// ---------------- K4b: deconv as MFMA GEMM (m97 structure, gemm_bt) ----------------
// C[m=4096][n=1024] = sum_k A[m][k] * B[n][k], K=2304
// A[(Qy,Qx)][(dy,dx,nn)] = attnp[b][Qy+2-dy][Qx+2-dx][nn]  (padded, zero ring)
// out[b][4Qy+ry][4Qx+rx][c] = C/6,  n=(ry*4+rx)*64+c
__global__ __launch_bounds__(256) void k_gemm(const short* __restrict__ attnp, // full base
                                              const short* __restrict__ Bbf,   // base at batch b0
                                              float* __restrict__ out,
                                              int b0) {
  int mt = blockIdx.x;             // 0..31
  int nt = blockIdx.y;             // 0..7
  int bl = blockIdx.z;
  int b = b0 + bl;
  int tid = threadIdx.x;
  int wave = tid >> 6, lane = tid & 63;
  int wm = wave >> 1, wn = wave & 1;
  int quad = lane >> 4, l16 = lane & 15;

  __shared__ __align__(16) short As[128 * 32];
  __shared__ __align__(16) short Bs[128 * 32];

  f32x4 acc[4][4];
  #pragma unroll
  for (int i = 0; i < 4; ++i)
    #pragma unroll
    for (int j = 0; j < 4; ++j) acc[i][j] = (f32x4)0.f;

  const short* Ab = attnp + (size_t)b * 66 * 66 * 256;
  const short* Bb = Bbf + (size_t)bl * 1024 * 2304 + (size_t)(nt * 128) * 2304;

  int larow = lane >> 2;           // 0..15
  int lakq  = lane & 3;            // which 8-elem chunk of the 32-k row
  short* Adst = As + wave * 1024 + lane * 8;
  short* Bdst = Bs + wave * 1024 + lane * 8;

  for (int kb = 0; kb < 72; ++kb) {
    int s = kb >> 3;               // shift index (uniform)
    int dy = s / 3, dx = s % 3;
    int n0 = (kb & 7) * 32;        // n-offset within the 256-wide shift
    __syncthreads();
    #pragma unroll
    for (int t = 0; t < 2; ++t) {
      int rr = wave * 32 + t * 16 + larow;     // tile row 0..127
      int m = mt * 128 + rr;
      int hh = (m >> 6) + 2 - dy;              // padded coords
      int wwp = (m & 63) + 2 - dx;
      gload_lds16(Ab + ((size_t)(hh * 66 + wwp) << 8) + n0 + lakq * 8,
                  Adst + t * 512);
      gload_lds16(Bb + (size_t)rr * 2304 + kb * 32 + lakq * 8,
                  Bdst + t * 512);
    }
    __syncthreads();
    short8 af[4], bfr[4];
    #pragma unroll
    for (int i = 0; i < 4; ++i)
      af[i] = *(const short8*)(As + (wm * 64 + i * 16 + l16) * 32 + quad * 8);
    #pragma unroll
    for (int j = 0; j < 4; ++j)
      bfr[j] = *(const short8*)(Bs + (wn * 64 + j * 16 + l16) * 32 + quad * 8);
    #pragma unroll
    for (int i = 0; i < 4; ++i)
      #pragma unroll
      for (int j = 0; j < 4; ++j)
        acc[i][j] = __builtin_amdgcn_mfma_f32_16x16x32_bf16(af[i], bfr[j], acc[i][j], 0, 0, 0);
  }

  const float inv6 = 1.f / 6.f;
  #pragma unroll
  for (int i = 0; i < 4; ++i) {
    int mbase = mt * 128 + wm * 64 + i * 16 + quad * 4;
    #pragma unroll
    for (int j = 0; j < 4; ++j) {
      int n = nt * 128 + wn * 64 + j * 16 + l16;
      int r = n >> 6; int c = n & 63;
      int ry = r >> 2, rx = r & 3;
      #pragma unroll
      for (int reg = 0; reg < 4; ++reg) {
        int m = mbase + reg;
        int Qy = m >> 6, Qx = m & 63;
        out[(((size_t)b * 256 + 4 * Qy + ry) * 256 + (4 * Qx + rx)) * 64 + c]
            = acc[i][j][reg] * inv6;
      }
    }
  }
}

extern "C" void kernel_launch(void* const* d_in, const int* in_sizes, int n_in,
                              void* d_out, int out_size, void* d_ws, size_t ws_size,
                              hipStream_t stream) {
  const float* x           = (const float*)d_in[0];
  const float* theta_w     = (const float*)d_in[1];
  const float* theta_b     = (const float*)d_in[2];
  const float* theta_alpha = (const float*)d_in[3];
  const float* phi_w       = (const float*)d_in[4];
  const float* phi_b       = (const float*)d_in[5];
  const float* phi_alpha   = (const float*)d_in[6];
  const float* g_w         = (const float*)d_in[7];
  const float* g_b         = (const float*)d_in[8];
  const float* g_alpha     = (const float*)d_in[9];
  float* out = (float*)d_out;

  char* w = (char*)d_ws;
  size_t off = 0;
  auto alloc = [&](size_t bytes) { void* p = w + off; off += (bytes + 255) & ~255ull; return p; };
  float* theta  = (float*)alloc(8ull * 4096 * 32 * 4);     // 4 MB
  float* g      = (float*)alloc(8ull * 4096 * 64 * 4);     // 8 MB
  float* phi    = (float*)alloc(8ull * 256 * 32 * 4);
  float* phi_nT = (float*)alloc(8ull * 288 * 256 * 4);
  size_t attnp_bytes = 8ull * 66 * 66 * 256 * 2;           // 17.8 MB
  short* attnp  = (short*)alloc(attnp_bytes);
  size_t bbf_full = 8ull * 1024 * 2304 * 2;                // 37.7 MB
  bool full = (off + bbf_full) <= ws_size;
  short* Bbf = (short*)alloc(full ? bbf_full : bbf_full / 8);

  hipMemsetAsync(attnp, 0, attnp_bytes, stream);           // zero ring for padded attn
  hipLaunchKernelGGL(k_theta_g, dim3(BB * 64 * 64), dim3(64), 0, stream,
                     x, theta_w, theta_b, theta_alpha, g_w, g_b, g_alpha, theta, g);
  hipLaunchKernelGGL(k_phi, dim3(BB * 256), dim3(64), 0, stream,
                     x, phi_w, phi_b, phi_alpha, phi);
  hipLaunchKernelGGL(k_phin, dim3(BB * 256), dim3(320), 0, stream, phi, phi_nT);
  hipLaunchKernelGGL(k_attn, dim3(BB * 64 * 16), dim3(256), 0, stream,
                     theta, phi_nT, attnp);
  if (full) {
    hipLaunchKernelGGL(k_bgather, dim3(BB * 1024), dim3(256), 0, stream, g, Bbf);
    hipLaunchKernelGGL(k_gemm, dim3(32, 8, BB), dim3(256), 0, stream, attnp, Bbf, out, 0);
  } else {
    for (int b = 0; b < BB; ++b) {
      hipLaunchKernelGGL(k_bgather, dim3(1024), dim3(256), 0, stream,
                         g + (size_t)b * 4096 * 64, Bbf);
      hipLaunchKernelGGL(k_gemm, dim3(32, 8, 1), dim3(256), 0, stream, attnp, Bbf, out, b);
    }
  }
}

// Round 3
// 472.184 us; speedup vs baseline: 108.5143x; 1.8191x over previous
//
#include <hip/hip_runtime.h>
#include <math.h>

// Problem constants: B=8, H=W=64, C=64, CI=32, SCALE=4, PATCH=3, N=256
#define BB 8

typedef __attribute__((ext_vector_type(8))) short short8;   // 8 x bf16 bits
typedef __attribute__((ext_vector_type(4))) float f32x4;

__device__ inline short f2bf(float x) {          // fp32 -> bf16 (RNE)
  unsigned u = __builtin_bit_cast(unsigned, x);
  u += 0x7fffu + ((u >> 16) & 1u);
  return (short)(u >> 16);
}
__device__ inline float bf2f(short h) {
  unsigned u = ((unsigned)(unsigned short)h) << 16;
  return __builtin_bit_cast(float, u);
}

__device__ inline void gload_lds16(const void* g, void* l) {
  __builtin_amdgcn_global_load_lds(
      (const __attribute__((address_space(1))) void*)g,
      (__attribute__((address_space(3))) void*)l, 16, 0, 0);
}

// ---------------- K1: theta & g conv1x1 + prelu ----------------
// theta -> padded bf16 hi/lo arrays thetaPh/thetaPl [b][66][66][32] (ring pre-zeroed)
__global__ void k_theta_g(const float* __restrict__ x,
                          const float* __restrict__ theta_w, const float* __restrict__ theta_b,
                          const float* __restrict__ theta_alpha,
                          const float* __restrict__ g_w, const float* __restrict__ g_b,
                          const float* __restrict__ g_alpha,
                          short* __restrict__ thetaPh, short* __restrict__ thetaPl,
                          float* __restrict__ g) {
  int pix = blockIdx.x;            // b*4096 + h*64 + w
  int tid = threadIdx.x;           // 0..63
  int b = pix >> 12, h = (pix >> 6) & 63, w = pix & 63;
  __shared__ float xs[64];
  xs[tid] = x[(size_t)pix * 64 + tid];
  __syncthreads();
  float gacc = g_b[tid];
  #pragma unroll
  for (int k = 0; k < 64; ++k) gacc += xs[k] * g_w[k * 64 + tid];
  float ga = g_alpha[tid];
  g[(size_t)pix * 64 + tid] = gacc >= 0.f ? gacc : ga * gacc;
  if (tid < 32) {
    float tacc = theta_b[tid];
    #pragma unroll
    for (int k = 0; k < 64; ++k) tacc += xs[k] * theta_w[k * 32 + tid];
    float ta = theta_alpha[tid];
    float v = tacc >= 0.f ? tacc : ta * tacc;
    short hi = f2bf(v);
    short lo = f2bf(v - bf2f(hi));
    size_t off = ((size_t)(b * 66 + h + 1) * 66 + (w + 1)) * 32 + tid;
    thetaPh[off] = hi;
    thetaPl[off] = lo;
  }
}

// ---------------- K2a: bilinear 64->16 (exact 2x2 avg) + phi conv ----------------
__global__ void k_phi(const float* __restrict__ x,
                      const float* __restrict__ phi_w, const float* __restrict__ phi_b,
                      const float* __restrict__ phi_alpha,
                      float* __restrict__ phi) {
  int bid = blockIdx.x;            // b*256 + i*16 + j
  int b = bid >> 8; int ij = bid & 255; int i = ij >> 4; int j = ij & 15;
  int tid = threadIdx.x;           // 0..63
  __shared__ float ps[64];
  const float* xb = x + (size_t)b * 64 * 64 * 64;
  int r0 = 4 * i + 1, c0 = 4 * j + 1;
  float v = 0.25f * ( xb[((size_t)r0 * 64 + c0) * 64 + tid]
                    + xb[((size_t)r0 * 64 + c0 + 1) * 64 + tid]
                    + xb[((size_t)(r0 + 1) * 64 + c0) * 64 + tid]
                    + xb[((size_t)(r0 + 1) * 64 + c0 + 1) * 64 + tid]);
  ps[tid] = v;
  __syncthreads();
  if (tid < 32) {
    float acc = phi_b[tid];
    #pragma unroll
    for (int k = 0; k < 64; ++k) acc += ps[k] * phi_w[k * 32 + tid];
    float a = phi_alpha[tid];
    phi[(size_t)bid * 32 + tid] = acc >= 0.f ? acc : a * acc;
  }
}

// ---------------- K2b: phi patches, L2-normalize -> Bh/Bl [b][n=256][k=288] bf16 hi/lo ----------------
__global__ void k_phin(const float* __restrict__ phi,
                       short* __restrict__ Bh, short* __restrict__ Bl) {
  int bid = blockIdx.x;            // b*256 + n
  int b = bid >> 8; int n = bid & 255; int i = n >> 4; int j = n & 15;
  int t = threadIdx.x;             // 0..319 (288 active)
  float val = 0.f;
  if (t < 288) {
    int di = t / 96; int rem = t % 96; int dj = rem >> 5; int ci = rem & 31;
    int pi = i + di - 1, pj = j + dj - 1;
    if (pi >= 0 && pi < 16 && pj >= 0 && pj < 16)
      val = phi[(((size_t)b * 16 + pi) * 16 + pj) * 32 + ci];
  }
  float ss = val * val;
  for (int off = 32; off > 0; off >>= 1) ss += __shfl_down(ss, off);
  __shared__ float red[5];
  int wid = t >> 6, lane = t & 63;
  if (lane == 0) red[wid] = ss;
  __syncthreads();
  float tot = red[0] + red[1] + red[2] + red[3] + red[4];
  float scale = 1.f / fmaxf(sqrtf(tot), 1e-6f);
  if (t < 288) {
    float v = val * scale;
    short hi = f2bf(v);
    short lo = f2bf(v - bf2f(hi));
    size_t off = ((size_t)bid) * 288 + t;
    Bh[off] = hi;
    Bl[off] = lo;
  }
}

// ---------------- K3: scores via MFMA (bf16x3) + fused softmax -> attnp bf16 padded ----------------
// scores[m=4096][n=256] = sum_k theta_patch[m][k=288] * phi_n[n][k], fp32-accurate via
// K' = 864: [ah|ah|al] . [bh|bl|bh]. Then row softmax (x10), bf16 out.
__global__ __launch_bounds__(512) void k_sattn(const short* __restrict__ thetaPh,
                                               const short* __restrict__ thetaPl,
                                               const short* __restrict__ Bh,
                                               const short* __restrict__ Bl,
                                               short* __restrict__ attnp) {
  int mt = blockIdx.x;             // 0..31  (128 m-rows each)
  int b  = blockIdx.y;             // 0..7
  int tid = threadIdx.x;
  int w = tid >> 6, lane = tid & 63;
  int wm = w >> 2, wn = w & 3;
  int quad = lane >> 4, l16 = lane & 15;

  __shared__ __align__(16) short smem[32768];        // 64 KB
  short* As = smem;                                  // 128*32
  short* Bs = smem + 4096;                           // 256*32
  float* wred = (float*)(smem + 12288);              // 128*4 floats (disjoint)

  f32x4 acc[4][4];
  #pragma unroll
  for (int i = 0; i < 4; ++i)
    #pragma unroll
    for (int j = 0; j < 4; ++j) acc[i][j] = (f32x4)0.f;

  int ar = w * 16 + (lane >> 2);                     // As row 0..127
  int am = mt * 128 + ar;
  int aQy = am >> 6, aQx = am & 63;
  int achunk = (lane & 3) * 8;

  for (int kb = 0; kb < 27; ++kb) {
    int t = kb / 9, s = kb % 9;
    int di = s / 3, dj = s % 3;
    const short* Aarr = (t < 2) ? thetaPh : thetaPl;
    const short* Barr = (t == 1) ? Bl : Bh;
    __syncthreads();
    gload_lds16(Aarr + ((size_t)(b * 66 + aQy + di) * 66 + (aQx + dj)) * 32 + achunk,
                As + w * 512 + lane * 8);
    #pragma unroll
    for (int p = 0; p < 2; ++p) {
      int nl = w * 32 + p * 16 + (lane >> 2);
      gload_lds16(Barr + ((size_t)(b * 256 + nl)) * 288 + s * 32 + achunk,
                  Bs + w * 1024 + p * 512 + lane * 8);
    }
    __syncthreads();
    short8 af[4], bfr[4];
    #pragma unroll
    for (int i = 0; i < 4; ++i)
      af[i] = *(const short8*)(As + (wm * 64 + i * 16 + l16) * 32 + quad * 8);
    #pragma unroll
    for (int j = 0; j < 4; ++j)
      bfr[j] = *(const short8*)(Bs + (wn * 64 + j * 16 + l16) * 32 + quad * 8);
    #pragma unroll
    for (int i = 0; i < 4; ++i)
      #pragma unroll
      for (int j = 0; j < 4; ++j)
        acc[i][j] = __builtin_amdgcn_mfma_f32_16x16x32_bf16(af[i], bfr[j], acc[i][j], 0, 0, 0);
  }

  // ---- fused softmax over n=256 (rows m) ----
  // thread holds rows r = wm*64 + i*16 + quad*4 + reg, cols n = wn*64 + j*16 + l16
  float rmax[4][4];
  #pragma unroll
  for (int i = 0; i < 4; ++i)
    #pragma unroll
    for (int reg = 0; reg < 4; ++reg) {
      float m = -1e30f;
      #pragma unroll
      for (int j = 0; j < 4; ++j) m = fmaxf(m, acc[i][j][reg]);
      #pragma unroll
      for (int off = 1; off < 16; off <<= 1) m = fmaxf(m, __shfl_xor(m, off));
      rmax[i][reg] = m;
    }
  if (l16 == 0) {
    #pragma unroll
    for (int i = 0; i < 4; ++i)
      #pragma unroll
      for (int reg = 0; reg < 4; ++reg)
        wred[(wm * 64 + i * 16 + quad * 4 + reg) * 4 + wn] = rmax[i][reg];
  }
  __syncthreads();
  #pragma unroll
  for (int i = 0; i < 4; ++i)
    #pragma unroll
    for (int reg = 0; reg < 4; ++reg) {
      int r = wm * 64 + i * 16 + quad * 4 + reg;
      rmax[i][reg] = fmaxf(fmaxf(wred[r * 4 + 0], wred[r * 4 + 1]),
                           fmaxf(wred[r * 4 + 2], wred[r * 4 + 3]));
    }
  __syncthreads();
  float rsum[4][4];
  #pragma unroll
  for (int i = 0; i < 4; ++i)
    #pragma unroll
    for (int reg = 0; reg < 4; ++reg) {
      float s = 0.f;
      #pragma unroll
      for (int j = 0; j < 4; ++j) {
        float e = expf((acc[i][j][reg] - rmax[i][reg]) * 10.f);
        acc[i][j][reg] = e;
        s += e;
      }
      #pragma unroll
      for (int off = 1; off < 16; off <<= 1) s += __shfl_xor(s, off);
      rsum[i][reg] = s;
    }
  if (l16 == 0) {
    #pragma unroll
    for (int i = 0; i < 4; ++i)
      #pragma unroll
      for (int reg = 0; reg < 4; ++reg)
        wred[(wm * 64 + i * 16 + quad * 4 + reg) * 4 + wn] = rsum[i][reg];
  }
  __syncthreads();
  #pragma unroll
  for (int i = 0; i < 4; ++i)
    #pragma unroll
    for (int reg = 0; reg < 4; ++reg) {
      int r = wm * 64 + i * 16 + quad * 4 + reg;
      float tot = wred[r * 4 + 0] + wred[r * 4 + 1] + wred[r * 4 + 2] + wred[r * 4 + 3];
      rsum[i][reg] = 1.f / tot;
    }
  __syncthreads();                                   // wred consumed; reuse smem as out stage
  #pragma unroll
  for (int i = 0; i < 4; ++i)
    #pragma unroll
    for (int reg = 0; reg < 4; ++reg) {
      int r = wm * 64 + i * 16 + quad * 4 + reg;
      #pragma unroll
      for (int j = 0; j < 4; ++j)
        smem[r * 256 + wn * 64 + j * 16 + l16] = f2bf(acc[i][j][reg] * rsum[i][reg]);
    }
  __syncthreads();
  {
    int r2 = tid >> 2, c2 = (tid & 3) * 64;
    int m2 = mt * 128 + r2;
    int Qy = m2 >> 6, Qx = m2 & 63;
    short8* dst = (short8*)(attnp + ((size_t)(b * 66 + Qy + 1) * 66 + (Qx + 1)) * 256 + c2);
    #pragma unroll
    for (int q = 0; q < 8; ++q) dst[q] = *(const short8*)(smem + r2 * 256 + c2 + q * 8);
  }
}

// ---------------- K4a: gather g -> Bbf[b][n=(ry,rx,c)=1024][k=(dy,dx,i,j)=2304] bf16 ----------------
__global__ __launch_bounds__(256) void k_bgather(const float* __restrict__ g,
                                                 short* __restrict__ Bbf) {
  int bid = blockIdx.x;            // bl*1024 + n
  int bl = bid >> 10; int n = bid & 1023;
  int r = n >> 6; int ry = r >> 2; int rx = r & 3; int c = n & 63;
  int tid = threadIdx.x;           // = i*16 + j
  int i = tid >> 4; int j = tid & 15;
  const float* gb = g + (size_t)bl * 64 * 64 * 64;
  short* dst = Bbf + ((size_t)bl * 1024 + n) * 2304;
  #pragma unroll
  for (int s = 0; s < 9; ++s) {
    int dy = s / 3, dx = s % 3;
    int row = 4 * i + ry + 4 * dy - 4;
    int col = 4 * j + rx + 4 * dx - 4;
    float v = 0.f;
    if (row >= 0 && row < 64 && col >= 0 && col < 64)
      v = gb[(((size_t)row << 6) + col) * 64 + c];
    dst[s * 256 + tid] = f2bf(v);
  }
}

// ---------------- K4b: deconv as MFMA GEMM ----------------
__global__ __launch_bounds__(256) void k_gemm(const short* __restrict__ attnp,
                                              const short* __restrict__ Bbf,
                                              float* __restrict__ out,
                                              int b0) {
  int mt = blockIdx.x;             // 0..31
  int nt = blockIdx.y;             // 0..7
  int bl = blockIdx.z;
  int b = b0 + bl;
  int tid = threadIdx.x;
  int wave = tid >> 6, lane = tid & 63;
  int wm = wave >> 1, wn = wave & 1;
  int quad = lane >> 4, l16 = lane & 15;

  __shared__ __align__(16) short As[128 * 32];
  __shared__ __align__(16) short Bs[128 * 32];

  f32x4 acc[4][4];
  #pragma unroll
  for (int i = 0; i < 4; ++i)
    #pragma unroll
    for (int j = 0; j < 4; ++j) acc[i][j] = (f32x4)0.f;

  const short* Ab = attnp + (size_t)b * 66 * 66 * 256;
  const short* Bb = Bbf + (size_t)bl * 1024 * 2304 + (size_t)(nt * 128) * 2304;

  int larow = lane >> 2;
  int lakq  = lane & 3;
  short* Adst = As + wave * 1024 + lane * 8;
  short* Bdst = Bs + wave * 1024 + lane * 8;

  for (int kb = 0; kb < 72; ++kb) {
    int s = kb >> 3;
    int dy = s / 3, dx = s % 3;
    int n0 = (kb & 7) * 32;
    __syncthreads();
    #pragma unroll
    for (int t = 0; t < 2; ++t) {
      int rr = wave * 32 + t * 16 + larow;
      int m = mt * 128 + rr;
      int hh = (m >> 6) + 2 - dy;
      int wwp = (m & 63) + 2 - dx;
      gload_lds16(Ab + ((size_t)(hh * 66 + wwp) << 8) + n0 + lakq * 8,
                  Adst + t * 512);
      gload_lds16(Bb + (size_t)rr * 2304 + kb * 32 + lakq * 8,
                  Bdst + t * 512);
    }
    __syncthreads();
    short8 af[4], bfr[4];
    #pragma unroll
    for (int i = 0; i < 4; ++i)
      af[i] = *(const short8*)(As + (wm * 64 + i * 16 + l16) * 32 + quad * 8);
    #pragma unroll
    for (int j = 0; j < 4; ++j)
      bfr[j] = *(const short8*)(Bs + (wn * 64 + j * 16 + l16) * 32 + quad * 8);
    #pragma unroll
    for (int i = 0; i < 4; ++i)
      #pragma unroll
      for (int j = 0; j < 4; ++j)
        acc[i][j] = __builtin_amdgcn_mfma_f32_16x16x32_bf16(af[i], bfr[j], acc[i][j], 0, 0, 0);
  }

  const float inv6 = 1.f / 6.f;
  #pragma unroll
  for (int i = 0; i < 4; ++i) {
    int mbase = mt * 128 + wm * 64 + i * 16 + quad * 4;
    #pragma unroll
    for (int j = 0; j < 4; ++j) {
      int n = nt * 128 + wn * 64 + j * 16 + l16;
      int r = n >> 6; int c = n & 63;
      int ry = r >> 2, rx = r & 3;
      #pragma unroll
      for (int reg = 0; reg < 4; ++reg) {
        int m = mbase + reg;
        int Qy = m >> 6, Qx = m & 63;
        out[(((size_t)b * 256 + 4 * Qy + ry) * 256 + (4 * Qx + rx)) * 64 + c]
            = acc[i][j][reg] * inv6;
      }
    }
  }
}

extern "C" void kernel_launch(void* const* d_in, const int* in_sizes, int n_in,
                              void* d_out, int out_size, void* d_ws, size_t ws_size,
                              hipStream_t stream) {
  const float* x           = (const float*)d_in[0];
  const float* theta_w     = (const float*)d_in[1];
  const float* theta_b     = (const float*)d_in[2];
  const float* theta_alpha = (const float*)d_in[3];
  const float* phi_w       = (const float*)d_in[4];
  const float* phi_b       = (const float*)d_in[5];
  const float* phi_alpha   = (const float*)d_in[6];
  const float* g_w         = (const float*)d_in[7];
  const float* g_b         = (const float*)d_in[8];
  const float* g_alpha     = (const float*)d_in[9];
  float* out = (float*)d_out;

  char* w = (char*)d_ws;
  size_t off = 0;
  auto alloc = [&](size_t bytes) { void* p = w + off; off += (bytes + 255) & ~255ull; return p; };
  float* g       = (float*)alloc(8ull * 4096 * 64 * 4);       // 8 MB
  float* phi     = (float*)alloc(8ull * 256 * 32 * 4);
  size_t thp_bytes = 8ull * 66 * 66 * 32 * 2;                 // 2.23 MB
  short* thetaPh = (short*)alloc(thp_bytes);
  short* thetaPl = (short*)alloc(thp_bytes);
  short* Bh      = (short*)alloc(8ull * 256 * 288 * 2);       // 1.18 MB
  short* Bl      = (short*)alloc(8ull * 256 * 288 * 2);
  size_t attnp_bytes = 8ull * 66 * 66 * 256 * 2;              // 17.8 MB
  short* attnp   = (short*)alloc(attnp_bytes);
  size_t bbf_full = 8ull * 1024 * 2304 * 2;                   // 37.7 MB
  bool full = (off + bbf_full) <= ws_size;
  short* Bbf = (short*)alloc(full ? bbf_full : bbf_full / 8);

  hipMemsetAsync(thetaPh, 0, thp_bytes, stream);
  hipMemsetAsync(thetaPl, 0, thp_bytes, stream);
  hipMemsetAsync(attnp, 0, attnp_bytes, stream);

  hipLaunchKernelGGL(k_theta_g, dim3(BB * 64 * 64), dim3(64), 0, stream,
                     x, theta_w, theta_b, theta_alpha, g_w, g_b, g_alpha,
                     thetaPh, thetaPl, g);
  hipLaunchKernelGGL(k_phi, dim3(BB * 256), dim3(64), 0, stream,
                     x, phi_w, phi_b, phi_alpha, phi);
  hipLaunchKernelGGL(k_phin, dim3(BB * 256), dim3(320), 0, stream, phi, Bh, Bl);
  hipLaunchKernelGGL(k_sattn, dim3(32, BB), dim3(512), 0, stream,
                     thetaPh, thetaPl, Bh, Bl, attnp);
  if (full) {
    hipLaunchKernelGGL(k_bgather, dim3(BB * 1024), dim3(256), 0, stream, g, Bbf);
    hipLaunchKernelGGL(k_gemm, dim3(32, 8, BB), dim3(256), 0, stream, attnp, Bbf, out, 0);
  } else {
    for (int b = 0; b < BB; ++b) {
      hipLaunchKernelGGL(k_bgather, dim3(1024), dim3(256), 0, stream,
                         g + (size_t)b * 4096 * 64, Bbf);
      hipLaunchKernelGGL(k_gemm, dim3(32, 8, 1), dim3(256), 0, stream, attnp, Bbf, out, b);
    }
  }
}